// Round 2
// baseline (1691.295 us; speedup 1.0000x reference)
//
#include <hip/hip_runtime.h>
#include <math.h>

#define DIM 1024
#define NSUB 1024
#define KEYD 256
#define CODED 128
#define NTOK 8192

// ---------------- fp32 GEMM (NT): C[M,N] = A[M,K] * B[N,K]^T, optional silu
// 128x128 block tile, 256 threads, 8x8 micro-tile, float4 global loads.
// Accumulation is a single fp32 FMA chain in ascending k order per output —
// chosen deliberately to correlate rounding with BLAS/cublas prefix sums
// (the reference's selection decisions depend on fp32 score rounding).
template<int SILU>
__global__ __launch_bounds__(256) void sgemm_nt(
    const float* __restrict__ A, const float* __restrict__ B, float* __restrict__ C,
    int M, int N, int K, int lda, int ldb, int ldc)
{
  __shared__ float As[8][128];
  __shared__ float Bs[8][128];
  const int tid = threadIdx.x;
  const int m0 = blockIdx.y * 128, n0 = blockIdx.x * 128;
  const int lrow = tid >> 1;        // 0..127
  const int lk   = (tid & 1) * 4;   // 0 or 4
  const int tx = tid & 15, ty = tid >> 4;
  float acc[8][8] = {{0.f}};
  const float* Ap = A + (size_t)(m0 + lrow) * lda + lk;
  const float* Bp = B + (size_t)(n0 + lrow) * ldb + lk;
  for (int kt = 0; kt < K; kt += 8) {
    float4 av = *(const float4*)(Ap + kt);
    float4 bv = *(const float4*)(Bp + kt);
    __syncthreads();
    As[lk + 0][lrow] = av.x; As[lk + 1][lrow] = av.y;
    As[lk + 2][lrow] = av.z; As[lk + 3][lrow] = av.w;
    Bs[lk + 0][lrow] = bv.x; Bs[lk + 1][lrow] = bv.y;
    Bs[lk + 2][lrow] = bv.z; Bs[lk + 3][lrow] = bv.w;
    __syncthreads();
#pragma unroll
    for (int k = 0; k < 8; ++k) {
      float a[8], b[8];
      *(float4*)&a[0] = *(const float4*)&As[k][ty * 8];
      *(float4*)&a[4] = *(const float4*)&As[k][ty * 8 + 4];
      *(float4*)&b[0] = *(const float4*)&Bs[k][tx * 8];
      *(float4*)&b[4] = *(const float4*)&Bs[k][tx * 8 + 4];
#pragma unroll
      for (int i = 0; i < 8; ++i)
#pragma unroll
        for (int j = 0; j < 8; ++j)
          acc[i][j] = fmaf(a[i], b[j], acc[i][j]);
    }
  }
#pragma unroll
  for (int i = 0; i < 8; ++i) {
    float* Cp = C + (size_t)(m0 + ty * 8 + i) * ldc + n0 + tx * 8;
    float v[8];
#pragma unroll
    for (int j = 0; j < 8; ++j) {
      float z = acc[i][j];
      if (SILU) z = z / (1.0f + expf(-z));
      v[j] = z;
    }
    *(float4*)(Cp)     = *(float4*)&v[0];
    *(float4*)(Cp + 4) = *(float4*)&v[4];
  }
}

// ---------------- top-k + softmax + code gather ----------------------------
// Sort key (u64): bits 16..47 = monotone-mapped fp32 (lossless), bits 0..15 =
// (1023 - idx). Descending sort => value desc, ties by LOWEST index — exactly
// jax.lax.top_k semantics on fp32 values.
__device__ inline unsigned int fmap32(float f) {
  unsigned int u = __float_as_uint(f);
  return (u >> 31) ? ~u : (u | 0x80000000u);
}

__device__ inline void bitonic_desc(unsigned long long* k, int tid) {
#pragma unroll 1
  for (int size = 2; size <= 1024; size <<= 1) {
#pragma unroll 1
    for (int stride = size >> 1; stride > 0; stride >>= 1) {
      __syncthreads();
#pragma unroll
      for (int v = 0; v < 4; ++v) {
        int i = tid + v * 256;
        int l = i ^ stride;
        if (l > i) {
          unsigned long long a = k[i], b = k[l];
          bool desc = ((i & size) == 0);
          bool sw = desc ? (a < b) : (a > b);
          if (sw) { k[i] = b; k[l] = a; }
        }
      }
    }
  }
  __syncthreads();
}

__global__ __launch_bounds__(256) void topk_mix(
    const float* __restrict__ scores,    // [NTOK][2048] (a: 0..1023, b: 1024..2047)
    const float* __restrict__ codes,     // [NSUB*NSUB][CODED]
    float* __restrict__ mixed)           // [NTOK][CODED]
{
  __shared__ unsigned long long keys[1024];
  __shared__ float ta_s[32], tb_s[32], cs_s[32], ev[32];
  __shared__ int ta_i[32], tb_i[32], cidx[32];
  __shared__ float cw[32];
  __shared__ float red[128];
  __shared__ float wsum;
  const int tid = threadIdx.x;
  const int token = blockIdx.x;
  const float* row = scores + (size_t)token * 2048;

  // top-32 of scores_a (fp32 values, jax tie-break)
  for (int i = tid; i < 1024; i += 256)
    keys[i] = ((unsigned long long)fmap32(row[i]) << 16) | (unsigned long long)(1023 - i);
  bitonic_desc(keys, tid);
  if (tid < 32) {
    int idx = 1023 - (int)(keys[tid] & 0xFFFFULL);
    ta_i[tid] = idx; ta_s[tid] = row[idx];
  }
  __syncthreads();
  // top-32 of scores_b
  for (int i = tid; i < 1024; i += 256)
    keys[i] = ((unsigned long long)fmap32(row[1024 + i]) << 16) | (unsigned long long)(1023 - i);
  bitonic_desc(keys, tid);
  if (tid < 32) {
    int idx = 1023 - (int)(keys[tid] & 0xFFFFULL);
    tb_i[tid] = idx; tb_s[tid] = row[1024 + idx];
  }
  __syncthreads();
  // 1024 candidates = ta_s[ra] + tb_s[rb] (single fp32 add — matches ref
  // bit-exactly given identical inputs), position p = ra*32+rb (jax order)
  for (int p = tid; p < 1024; p += 256) {
    float s = ta_s[p >> 5] + tb_s[p & 31];
    keys[p] = ((unsigned long long)fmap32(s) << 16) | (unsigned long long)(1023 - p);
  }
  bitonic_desc(keys, tid);
  if (tid < 32) {
    int p = 1023 - (int)(keys[tid] & 0xFFFFULL);
    cs_s[tid] = ta_s[p >> 5] + tb_s[p & 31];
    cidx[tid] = ta_i[p >> 5] * NSUB + tb_i[p & 31];
  }
  __syncthreads();
  // fp32 softmax over the 32 selected; cs_s[0] is the max (sorted desc).
  // logits = scores / sqrt(2*KEY_DIM), subtract max, exp, normalize.
  if (tid < 32) {
    float l  = cs_s[tid] / 22.627416997969522f;
    float l0 = cs_s[0]   / 22.627416997969522f;
    ev[tid] = expf(l - l0);
  }
  __syncthreads();
  if (tid == 0) {
    float s = 0.f;
    for (int k = 0; k < 32; ++k) s += ev[k];
    wsum = s;
  }
  __syncthreads();
  if (tid < 32) cw[tid] = ev[tid] / wsum;
  __syncthreads();
  // mixed[c] = sum_k w_k * codes[idx_k][c]; 2 halves of k over 256 threads
  const int c = tid & 127, half = tid >> 7;
  float acc = 0.f;
  for (int k = half * 16; k < half * 16 + 16; ++k)
    acc += cw[k] * codes[(size_t)cidx[k] * CODED + c];
  if (half) red[c] = acc;
  __syncthreads();
  if (tid < 128) mixed[(size_t)token * CODED + tid] = acc + red[tid];
}

extern "C" void kernel_launch(void* const* d_in, const int* in_sizes, int n_in,
                              void* d_out, int out_size, void* d_ws, size_t ws_size,
                              hipStream_t stream)
{
  const float* x     = (const float*)d_in[0];
  const float* Wq    = (const float*)d_in[1];
  const float* key_a = (const float*)d_in[2];
  const float* key_b = (const float*)d_in[3];
  const float* codes = (const float*)d_in[4];
  const float* W1    = (const float*)d_in[5];
  const float* W2    = (const float*)d_in[6];
  float* out = (float*)d_out;

  // ws layout: q f32 [0,16MB), scores f32 [16,80MB), mixed [80,84MB),
  // h f32 [84,116MB)
  char* ws = (char*)d_ws;
  float* q      = (float*)(ws);
  float* scores = (float*)(ws + (size_t)16 * 1024 * 1024);
  float* mixed  = (float*)(ws + (size_t)80 * 1024 * 1024);
  float* h      = (float*)(ws + (size_t)84 * 1024 * 1024);

  // q = x @ Wq^T  (fp32, sequential-k accumulation like the reference)
  sgemm_nt<0><<<dim3(512 / 128, NTOK / 128), 256, 0, stream>>>(
      x, Wq, q, NTOK, 512, DIM, DIM, DIM, 512);
  // scores_a = q[:, :256] @ key_a^T ; scores_b = q[:, 256:] @ key_b^T
  sgemm_nt<0><<<dim3(NSUB / 128, NTOK / 128), 256, 0, stream>>>(
      q, key_a, scores, NTOK, NSUB, KEYD, 512, KEYD, 2048);
  sgemm_nt<0><<<dim3(NSUB / 128, NTOK / 128), 256, 0, stream>>>(
      q + KEYD, key_b, scores + NSUB, NTOK, NSUB, KEYD, 512, KEYD, 2048);
  // per-token product-key top-k -> softmax -> code mix (all fp32)
  topk_mix<<<NTOK, 256, 0, stream>>>(scores, codes, mixed);
  // h = silu(mixed @ W1^T)
  sgemm_nt<1><<<dim3(DIM / 128, NTOK / 128), 256, 0, stream>>>(
      mixed, W1, h, NTOK, DIM, CODED, CODED, CODED, DIM);
  // out = h @ W2^T
  sgemm_nt<0><<<dim3(DIM / 128, NTOK / 128), 256, 0, stream>>>(
      h, W2, out, NTOK, DIM, DIM, DIM, DIM, DIM);
}